// Round 6
// baseline (98.803 us; speedup 1.0000x reference)
//
#include <hip/hip_runtime.h>

#define NN 256   // nodes per graph
#define DM 128   // gcn hidden dim
#define NH 4     // heads
#define LK 72    // row stride (elems) for ks/qs/P-slices
#define LT 264   // row stride for vsT/RsT

typedef __bf16 bf16;
typedef __attribute__((ext_vector_type(8))) __bf16 bf16x8;
typedef __attribute__((ext_vector_type(4))) float f32x4;
typedef __attribute__((ext_vector_type(16))) float f32x16;
typedef __attribute__((ext_vector_type(4))) unsigned int u32x4;

static __device__ __forceinline__ unsigned short f2b(float f) {
  return __builtin_bit_cast(unsigned short, (__bf16)f);
}
static __device__ __forceinline__ bf16x8 ldf(const unsigned short* p) {
  return *(const bf16x8*)p;
}
static __device__ __forceinline__ void st4(unsigned short* p, float a, float b, float c, float d) {
  ushort4 v; v.x = f2b(a); v.y = f2b(b); v.z = f2b(c); v.w = f2b(d);
  *(ushort4*)p = v;
}
static __device__ __forceinline__ unsigned cvtpk(float lo, float hi) {
  unsigned r;
  asm("v_cvt_pk_bf16_f32 %0, %1, %2" : "=v"(r) : "v"(lo), "v"(hi));
  return r;
}
// fragment from two 8B LDS reads (k-slot mapping: j<4 -> p0[j], j>=4 -> p1[j-4])
static __device__ __forceinline__ bf16x8 ld2(const unsigned short* p0, const unsigned short* p1) {
  u32x4 t;
  t.x = *(const unsigned*)(p0);
  t.y = *(const unsigned*)(p0 + 2);
  t.z = *(const unsigned*)(p1);
  t.w = *(const unsigned*)(p1 + 2);
  return __builtin_bit_cast(bf16x8, t);
}

#define MFMA16(a,b,c) __builtin_amdgcn_mfma_f32_16x16x32_bf16((a),(b),(c),0,0,0)
#define MFMA32(a,b,c) __builtin_amdgcn_mfma_f32_32x32x16_bf16((a),(b),(c),0,0,0)
#define Z4  {0.f,0.f,0.f,0.f}
#define Z16 {0.f,0.f,0.f,0.f,0.f,0.f,0.f,0.f,0.f,0.f,0.f,0.f,0.f,0.f,0.f,0.f}

// ---- d_ws layout (unsigned short elements) ----
#define XELEMS (256u * 16u * 256u * 8u)   // x2 [cb][dg16][n256][8]
#define WQO 0
#define WKO 32768
#define WVO 65536
#define WFO 98304
#define WELEMS 114688u                    // wq2/wk2/wv2 [dg16][col256][8] + wfc2 [dg32][col64][8]
#define OELEMS (256u * 64u * 256u)        // O [cb][d64][h*64+e]

__global__ void prep_x_kernel(const float* __restrict__ gnn, unsigned short* __restrict__ x2) {
  const int tid = blockIdx.x * 256 + threadIdx.x;   // 0..262143
  const int cb  = tid >> 10;
  const int r   = tid & 1023;
  const int dgq = r >> 8;        // 0..3
  const int n   = r & 255;
  const float* src = gnn + ((size_t)cb * 256 + n) * 128;
  unsigned short* dstb = x2 + (size_t)cb * (16 * 256 * 8);
#pragma unroll
  for (int i = 0; i < 4; ++i) {
    const int dg = dgq * 4 + i;
    float4 a = *(const float4*)(src + dg * 8);
    float4 b = *(const float4*)(src + dg * 8 + 4);
    ushort4 u0, u1;
    u0.x = f2b(a.x); u0.y = f2b(a.y); u0.z = f2b(a.z); u0.w = f2b(a.w);
    u1.x = f2b(b.x); u1.y = f2b(b.y); u1.z = f2b(b.z); u1.w = f2b(b.w);
    ushort4* d = (ushort4*)(dstb + ((size_t)dg * 256 + n) * 8);
    d[0] = u0; d[1] = u1;
  }
}

__global__ void prep_w_kernel(const float* __restrict__ Wq, const float* __restrict__ Wk,
                              const float* __restrict__ Wv, const float* __restrict__ Wfc,
                              unsigned short* __restrict__ w2) {
  const int tid = blockIdx.x * 256 + threadIdx.x;  // 0..14335
  if (tid < 12288) {
    const int wi  = tid >> 12;          // 0:q 1:k 2:v
    const int r   = tid & 4095;
    const int dg  = r >> 8, col = r & 255;
    const float* W = (wi == 0) ? Wq : ((wi == 1) ? Wk : Wv);
    unsigned short* d = w2 + wi * 32768 + ((size_t)dg * 256 + col) * 8;
#pragma unroll
    for (int j = 0; j < 8; ++j) d[j] = f2b(W[(size_t)(dg * 8 + j) * 256 + col]);
  } else if (tid < 14336) {
    const int r  = tid - 12288;
    const int dg = r >> 6, col = r & 63;
    unsigned short* d = w2 + WFO + ((size_t)dg * 64 + col) * 8;
#pragma unroll
    for (int j = 0; j < 8; ++j) d[j] = f2b(Wfc[(size_t)(dg * 8 + j) * 64 + col]);
  }
}

// ======================= main per-(cb,head) kernel =======================
__global__ __launch_bounds__(512, 4)
void vlrgat_head_kernel(const unsigned short* __restrict__ wsx,
                        const unsigned short* __restrict__ wsw,
                        unsigned short* __restrict__ wso)
{
  __shared__ __align__(16) unsigned short ks [NN * LK];   // K [n=256][d=64] ; later aliased as RsT [e=64][LT]
  __shared__ __align__(16) unsigned short vsT[64 * LT];   // V^T [e=64][n=256]
  __shared__ __align__(16) float sums[NN];                // per-q exp sums

  const int t   = threadIdx.x;
  const int w   = t >> 6;     // wave 0..7
  const int l   = t & 63;
  const int l31 = l & 31;
  const int lh  = l >> 5;
  const int g   = w & 3;
  const int bid = blockIdx.x;
  const int cb  = bid >> 2;
  const int h   = bid & 3;
  const unsigned short* const xw = wsx + (size_t)cb * (16 * 256 * 8);

  // ---------------- K/V weight fragments (standard slot order) ----------------
  const int woA = (w < 4) ? WKO : WVO;
  bf16x8 wA[2][8];
#pragma unroll
  for (int e = 0; e < 2; ++e)
#pragma unroll
    for (int c = 0; c < 8; ++c)
      wA[e][c] = ldf(wsw + woA + (((size_t)(c * 2 + lh)) * 256 + h * 64 + e * 32 + l31) * 8);

  // ---------------- projection ----------------
  // wave w owns q rows [32w,32w+32); Q stays in registers (natural order)
  u32x4 qu[4];
  const int hw = w >> 2;     // half containing this wave's own rows
#pragma unroll
  for (int half = 0; half < 2; ++half) {
    const int n0 = half * 128 + g * 32;
    bf16x8 xa[8];
#pragma unroll
    for (int c = 0; c < 8; ++c)
      xa[c] = ldf(xw + (((size_t)(c * 2 + lh)) * 256 + n0 + l31) * 8);
    if (w < 4) {
      // K -> ks[n][d] (packed st4)
#pragma unroll
      for (int e = 0; e < 2; ++e) {
        f32x16 a = Z16;
#pragma unroll
        for (int c = 0; c < 8; ++c) a = MFMA32(wA[e][c], xa[c], a);
#pragma unroll
        for (int g2 = 0; g2 < 4; ++g2)
          st4(&ks[(n0 + l31) * LK + e * 32 + g2 * 8 + lh * 4],
              a[g2*4], a[g2*4+1], a[g2*4+2], a[g2*4+3]);
      }
    } else {
      // V -> vsT[e][n]
#pragma unroll
      for (int e = 0; e < 2; ++e) {
        f32x16 a = Z16;
#pragma unroll
        for (int c = 0; c < 8; ++c) a = MFMA32(xa[c], wA[e][c], a);
#pragma unroll
        for (int g2 = 0; g2 < 4; ++g2)
          st4(&vsT[(e * 32 + l31) * LT + n0 + g2 * 8 + lh * 4],
              a[g2*4], a[g2*4+1], a[g2*4+2], a[g2*4+3]);
      }
    }
    if (half == hw) {
      // Q for own rows, both e-blocks, kept in regs (natural slot order)
#pragma unroll
      for (int e = 0; e < 2; ++e) {
        bf16x8 wQ[8];
#pragma unroll
        for (int c = 0; c < 8; ++c)
          wQ[c] = ldf(wsw + WQO + (((size_t)(c * 2 + lh)) * 256 + h * 64 + e * 32 + l31) * 8);
        f32x16 a = Z16;
#pragma unroll
        for (int c = 0; c < 8; ++c) a = MFMA32(wQ[c], xa[c], a);
        const float S = 0.125f;   // 1/sqrt(64)
        qu[e*2]   = (u32x4){cvtpk(a[0]*S,  a[1]*S),  cvtpk(a[2]*S,  a[3]*S),
                            cvtpk(a[4]*S,  a[5]*S),  cvtpk(a[6]*S,  a[7]*S)};
        qu[e*2+1] = (u32x4){cvtpk(a[8]*S,  a[9]*S),  cvtpk(a[10]*S, a[11]*S),
                            cvtpk(a[12]*S, a[13]*S), cvtpk(a[14]*S, a[15]*S)};
      }
    }
  }
  __syncthreads();   // B3: K/V published

  // ---------------- S + softmax + R, fully wave-local ----------------
  // qf[kt] slot (lh,j) <-> d = 16kt + 8*(j>>2) + 4lh + (j&3); K read with matching ld2
  f32x16 racc0 = Z16, racc1 = Z16;
  float psum = 0.f;
  const int ko1 = 4 * lh, ko2 = 8 + 4 * lh;
#pragma unroll
  for (int mb = 0; mb < 8; ++mb) {
    const unsigned short* krow = &ks[(mb * 32 + l31) * LK];
    f32x16 s = Z16;
#pragma unroll
    for (int kt = 0; kt < 4; ++kt) {
      bf16x8 kf = ld2(krow + kt * 16 + ko1, krow + kt * 16 + ko2);
      s = MFMA32(kf, __builtin_bit_cast(bf16x8, qu[kt]), s);
    }
#pragma unroll
    for (int i = 0; i < 16; ++i) { s[i] = __expf(s[i]); psum += s[i]; }
    // pack P (natural order), feed R immediately
    u32x4 pu0 = (u32x4){cvtpk(s[0], s[1]),   cvtpk(s[2], s[3]),
                        cvtpk(s[4], s[5]),   cvtpk(s[6], s[7])};
    u32x4 pu1 = (u32x4){cvtpk(s[8], s[9]),   cvtpk(s[10], s[11]),
                        cvtpk(s[12], s[13]), cvtpk(s[14], s[15])};
#pragma unroll
    for (int b = 0; b < 2; ++b) {
      bf16x8 pf = __builtin_bit_cast(bf16x8, b ? pu1 : pu0);
      const unsigned short* v0 = &vsT[l31 * LT + mb * 32 + b * 16];
      const unsigned short* v1 = &vsT[(32 + l31) * LT + mb * 32 + b * 16];
      racc0 = MFMA32(pf, ld2(v0 + ko1, v0 + ko2), racc0);
      racc1 = MFMA32(pf, ld2(v1 + ko1, v1 + ko2), racc1);
    }
  }
  psum += __shfl_xor(psum, 32);
  sums[w * 32 + l31] = psum;   // lane <-> q; both lh write same value (benign)

  __syncthreads();   // B4: all ks reads + sums writes done

  // RsT[e][q] normalized, aliasing ks region
  unsigned short* const RsT = ks;
#pragma unroll
  for (int g2 = 0; g2 < 4; ++g2) {
    float4 sv = *(const float4*)&sums[w * 32 + g2 * 8 + lh * 4];
    const float i0 = 1.f / sv.x, i1 = 1.f / sv.y, i2 = 1.f / sv.z, i3 = 1.f / sv.w;
    st4(&RsT[l31 * LT + w * 32 + g2 * 8 + lh * 4],
        racc0[g2*4]*i0, racc0[g2*4+1]*i1, racc0[g2*4+2]*i2, racc0[g2*4+3]*i3);
    st4(&RsT[(32 + l31) * LT + w * 32 + g2 * 8 + lh * 4],
        racc1[g2*4]*i0, racc1[g2*4+1]*i1, racc1[g2*4+2]*i2, racc1[g2*4+3]*i3);
  }
  __syncthreads();   // B5: RsT published

  // ---------------- O = V^T @ R (waves 0-3), write to ws ----------------
  if (w < 4) {
    const int db = (w >> 1) * 32, eb = (w & 1) * 32;
    f32x16 o = Z16;
#pragma unroll
    for (int kt = 0; kt < 16; ++kt)
      o = MFMA32(ldf(&vsT[(db + l31) * LT + kt * 16 + lh * 8]),
                 ldf(&RsT[(eb + l31) * LT + kt * 16 + lh * 8]), o);
    unsigned short* ob = wso + (size_t)cb * 64 * 256;
#pragma unroll
    for (int r = 0; r < 16; ++r) {
      const int d = db + (r & 3) + 8 * (r >> 2) + 4 * lh;
      ob[(size_t)d * 256 + h * 64 + eb + l31] = f2b(o[r]);
    }
  }
}

// ======================= epilogue: F = O @ Wfc, LN, LN =======================
__global__ __launch_bounds__(256, 4)
void fc_ln_kernel(const unsigned short* __restrict__ wso,
                  const unsigned short* __restrict__ wsw,
                  const float* __restrict__ ln1g, const float* __restrict__ ln1b,
                  const float* __restrict__ ln2g, const float* __restrict__ ln2b,
                  float* __restrict__ out)
{
  const int t  = threadIdx.x;
  const int w  = t >> 6;
  const int l  = t & 63;
  const int lr = l & 15;
  const int lg = l >> 4;
  const int cb = blockIdx.x;
  const unsigned short* ob = wso + (size_t)cb * 64 * 256;

  bf16x8 oa[8];
#pragma unroll
  for (int kt = 0; kt < 8; ++kt)
    oa[kt] = ldf(&ob[(w * 16 + lr) * 256 + kt * 32 + lg * 8]);
  f32x4 fa[4];
#pragma unroll
  for (int ct = 0; ct < 4; ++ct) {
    f32x4 a = Z4;
#pragma unroll
    for (int kt = 0; kt < 8; ++kt)
      a = MFMA16(oa[kt], ldf(wsw + WFO + (((size_t)(kt * 4 + lg)) * 64 + ct * 16 + lr) * 8), a);
    fa[ct] = a;
  }

  float g1v[4], b1v[4], g2v[4], b2v[4];
#pragma unroll
  for (int ct = 0; ct < 4; ++ct) {
    g1v[ct] = ln1g[ct * 16 + lr];
    b1v[ct] = ln1b[ct * 16 + lr];
    g2v[ct] = ln2g[ct * 16 + lr];
    b2v[ct] = ln2b[ct * 16 + lr];
  }
  const int bb = cb & 31;
  const int ch = cb >> 5;
  float* const obase = out + (size_t)(bb * 8 + ch) * 64 * 64;
#pragma unroll
  for (int r = 0; r < 4; ++r) {
    const int row = w * 16 + lg * 4 + r;
    float x0 = fa[0][r], x1 = fa[1][r], x2 = fa[2][r], x3 = fa[3][r];
    float mu = x0 + x1 + x2 + x3;
    mu += __shfl_xor(mu, 1); mu += __shfl_xor(mu, 2);
    mu += __shfl_xor(mu, 4); mu += __shfl_xor(mu, 8);
    mu *= 0.015625f;
    float d0 = x0 - mu, d1 = x1 - mu, d2 = x2 - mu, d3 = x3 - mu;
    float vr = d0*d0 + d1*d1 + d2*d2 + d3*d3;
    vr += __shfl_xor(vr, 1); vr += __shfl_xor(vr, 2);
    vr += __shfl_xor(vr, 4); vr += __shfl_xor(vr, 8);
    const float is1 = rsqrtf(vr * 0.015625f + 1e-6f);
    float y0 = d0*is1*g1v[0] + b1v[0];
    float y1 = d1*is1*g1v[1] + b1v[1];
    float y2 = d2*is1*g1v[2] + b1v[2];
    float y3 = d3*is1*g1v[3] + b1v[3];
    float mu2 = y0 + y1 + y2 + y3;
    mu2 += __shfl_xor(mu2, 1); mu2 += __shfl_xor(mu2, 2);
    mu2 += __shfl_xor(mu2, 4); mu2 += __shfl_xor(mu2, 8);
    mu2 *= 0.015625f;
    float e0 = y0-mu2, e1 = y1-mu2, e2 = y2-mu2, e3 = y3-mu2;
    float v2 = e0*e0 + e1*e1 + e2*e2 + e3*e3;
    v2 += __shfl_xor(v2, 1); v2 += __shfl_xor(v2, 2);
    v2 += __shfl_xor(v2, 4); v2 += __shfl_xor(v2, 8);
    const float is2 = rsqrtf(v2 * 0.015625f + 1e-6f);
    float* const op = obase + (size_t)row * 64;
    op[ 0 + lr] = e0*is2*g2v[0] + b2v[0];
    op[16 + lr] = e1*is2*g2v[1] + b2v[1];
    op[32 + lr] = e2*is2*g2v[2] + b2v[2];
    op[48 + lr] = e3*is2*g2v[3] + b2v[3];
  }
}

// ======================= fallback (round-5 verified, no-ws path) =======================
__global__ __launch_bounds__(512, 2)
void vlrgat_fallback(const float* __restrict__ gnn,
                     const float* __restrict__ Wq, const float* __restrict__ Wk,
                     const float* __restrict__ Wv, const float* __restrict__ Wfc,
                     const float* __restrict__ ln1g, const float* __restrict__ ln1b,
                     const float* __restrict__ ln2g, const float* __restrict__ ln2b,
                     float* __restrict__ out)
{
  __shared__ __align__(16) unsigned short ks [NN * LK];
  __shared__ __align__(16) unsigned short qs [NN * LK];
  __shared__ __align__(16) unsigned short vsT[64 * LT];
  __shared__ __align__(16) unsigned short U  [NN * LK];
  __shared__ __align__(16) float sums[NN];

  const int t   = threadIdx.x;
  const int w   = t >> 6;
  const int l   = t & 63;
  const int lr  = l & 15;
  const int lg  = l >> 4;
  const int l31 = l & 31;
  const int lh  = l >> 5;
  const int g   = w & 3;
  const int cb  = blockIdx.x;

  f32x16 oacc[NH];
#pragma unroll
  for (int h = 0; h < NH; ++h) oacc[h] = (f32x16)Z16;

  auto xfrag = [&](int n0, int c) -> bf16x8 {
    const float* p = gnn + ((size_t)cb * 256 + n0 + l31) * 128 + c * 16 + lh * 8;
    bf16x8 r;
#pragma unroll
    for (int j = 0; j < 8; ++j) r[j] = (bf16)p[j];
    return r;
  };
  auto wfrag = [&](const float* __restrict__ W, int c, int col) -> bf16x8 {
    bf16x8 r;
#pragma unroll
    for (int j = 0; j < 8; ++j) r[j] = (bf16)W[(size_t)(c * 16 + lh * 8 + j) * 256 + col];
    return r;
  };

#pragma unroll
  for (int h = 0; h < NH; ++h) {
    const float* const WAp = (w < 4) ? Wk : Wv;
    bf16x8 wA[2][8], wQ[8];
#pragma unroll
    for (int e = 0; e < 2; ++e)
#pragma unroll
      for (int c = 0; c < 8; ++c)
        wA[e][c] = wfrag(WAp, c, h * 64 + e * 32 + l31);
    const int qcol = h * 64 + ((w < 4) ? 0 : 32) + l31;
#pragma unroll
    for (int c = 0; c < 8; ++c)
      wQ[c] = wfrag(Wq, c, qcol);

    __syncthreads();

#pragma unroll
    for (int half = 0; half < 2; ++half) {
      const int n0 = half * 128 + g * 32;
      bf16x8 xa[8];
#pragma unroll
      for (int c = 0; c < 8; ++c) xa[c] = xfrag(n0, c);
      if (w < 4) {
#pragma unroll
        for (int e = 0; e < 2; ++e) {
          f32x16 a = Z16;
#pragma unroll
          for (int c = 0; c < 8; ++c) a = MFMA32(wA[e][c], xa[c], a);
#pragma unroll
          for (int g2 = 0; g2 < 4; ++g2)
            st4(&ks[(n0 + l31) * LK + e * 32 + g2 * 8 + lh * 4],
                a[g2*4], a[g2*4+1], a[g2*4+2], a[g2*4+3]);
        }
        f32x16 a = Z16;
#pragma unroll
        for (int c = 0; c < 8; ++c) a = MFMA32(wQ[c], xa[c], a);
#pragma unroll
        for (int g2 = 0; g2 < 4; ++g2)
          st4(&qs[(n0 + l31) * LK + g2 * 8 + lh * 4],
              a[g2*4]*0.125f, a[g2*4+1]*0.125f, a[g2*4+2]*0.125f, a[g2*4+3]*0.125f);
      } else {
#pragma unroll
        for (int e = 0; e < 2; ++e) {
          f32x16 a = Z16;
#pragma unroll
          for (int c = 0; c < 8; ++c) a = MFMA32(xa[c], wA[e][c], a);
#pragma unroll
          for (int g2 = 0; g2 < 4; ++g2)
            st4(&vsT[(e * 32 + l31) * LT + n0 + g2 * 8 + lh * 4],
                a[g2*4], a[g2*4+1], a[g2*4+2], a[g2*4+3]);
        }
        f32x16 a = Z16;
#pragma unroll
        for (int c = 0; c < 8; ++c) a = MFMA32(wQ[c], xa[c], a);
#pragma unroll
        for (int g2 = 0; g2 < 4; ++g2)
          st4(&qs[(n0 + l31) * LK + 32 + g2 * 8 + lh * 4],
              a[g2*4]*0.125f, a[g2*4+1]*0.125f, a[g2*4+2]*0.125f, a[g2*4+3]*0.125f);
      }
    }
    __syncthreads();

    bf16x8 qf[4];
#pragma unroll
    for (int kt = 0; kt < 4; ++kt)
      qf[kt] = ldf(&qs[(w * 32 + l31) * LK + kt * 16 + lh * 8]);
    unsigned short* const Pw = &U[(w * 32) * LK];
    f32x16 racc[2]; racc[0] = (f32x16)Z16; racc[1] = (f32x16)Z16;
    float psum = 0.f;
#pragma unroll
    for (int kh = 0; kh < 2; ++kh) {
      f32x16 sh[4];
#pragma unroll
      for (int mb = 0; mb < 4; ++mb) {
        sh[mb] = (f32x16)Z16;
#pragma unroll
        for (int kt = 0; kt < 4; ++kt)
          sh[mb] = MFMA32(ldf(&ks[((kh * 4 + mb) * 32 + l31) * LK + kt * 16 + lh * 8]),
                          qf[kt], sh[mb]);
      }
#pragma unroll
      for (int mb = 0; mb < 4; ++mb)
#pragma unroll
        for (int i = 0; i < 16; ++i) {
          sh[mb][i] = __expf(sh[mb][i]);
          psum += sh[mb][i];
        }
#pragma unroll
      for (int sl = 0; sl < 2; ++sl) {
#pragma unroll
        for (int mbl = 0; mbl < 2; ++mbl) {
          const f32x16& s = sh[sl * 2 + mbl];
#pragma unroll
          for (int g2 = 0; g2 < 4; ++g2)
            st4(&Pw[l31 * LK + mbl * 32 + g2 * 8 + lh * 4],
                s[g2*4], s[g2*4+1], s[g2*4+2], s[g2*4+3]);
        }
        const int kb = kh * 128 + sl * 64;
#pragma unroll
        for (int kt2 = 0; kt2 < 4; ++kt2) {
          bf16x8 pf = ldf(&Pw[l31 * LK + kt2 * 16 + lh * 8]);
          racc[0] = MFMA32(pf, ldf(&vsT[l31 * LT + kb + kt2 * 16 + lh * 8]), racc[0]);
          racc[1] = MFMA32(pf, ldf(&vsT[(32 + l31) * LT + kb + kt2 * 16 + lh * 8]), racc[1]);
        }
      }
    }
    psum += __shfl_xor(psum, 32);
    sums[w * 32 + l31] = psum;

    __syncthreads();

#pragma unroll
    for (int g2 = 0; g2 < 4; ++g2) {
      float4 sv = *(const float4*)&sums[w * 32 + g2 * 8 + lh * 4];
      const float i0 = 1.f / sv.x, i1 = 1.f / sv.y, i2 = 1.f / sv.z, i3 = 1.f / sv.w;
#pragma unroll
      for (int eb = 0; eb < 2; ++eb)
        st4(&U[(eb * 32 + l31) * LT + w * 32 + g2 * 8 + lh * 4],
            racc[eb][g2*4]*i0, racc[eb][g2*4+1]*i1, racc[eb][g2*4+2]*i2, racc[eb][g2*4+3]*i3);
    }
    __syncthreads();

    if (w < 4) {
      const int db = (w >> 1) * 32, eb = (w & 1) * 32;
#pragma unroll
      for (int kt = 0; kt < 16; ++kt)
        oacc[h] = MFMA32(ldf(&vsT[(db + l31) * LT + kt * 16 + lh * 8]),
                         ldf(&U  [(eb + l31) * LT + kt * 16 + lh * 8]), oacc[h]);
    }
  }

  __syncthreads();
  if (w < 4) {
    const int db = (w >> 1) * 32, eb = (w & 1) * 32;
#pragma unroll
    for (int h2 = 0; h2 < NH; ++h2)
#pragma unroll
      for (int g2 = 0; g2 < 4; ++g2)
#pragma unroll
        for (int r = 0; r < 4; ++r)
          U[(db + g2 * 8 + lh * 4 + r) * LT + h2 * 64 + eb + l31] = f2b(oacc[h2][g2*4+r]);
  }
  __syncthreads();

  if (w < 4) {
    bf16x8 oa[8];
#pragma unroll
    for (int kt = 0; kt < 8; ++kt)
      oa[kt] = ldf(&U[(w * 16 + lr) * LT + kt * 32 + lg * 8]);
    f32x4 fa[4];
#pragma unroll
    for (int ct = 0; ct < 4; ++ct) {
      f32x4 a = Z4;
#pragma unroll
      for (int kt = 0; kt < 8; ++kt) {
        bf16x8 wf;
#pragma unroll
        for (int j = 0; j < 8; ++j) wf[j] = (bf16)Wfc[(size_t)(kt * 32 + lg * 8 + j) * 64 + ct * 16 + lr];
        a = MFMA16(oa[kt], wf, a);
      }
      fa[ct] = a;
    }

    float g1v[4], b1v[4], g2v[4], b2v[4];
#pragma unroll
    for (int ct = 0; ct < 4; ++ct) {
      g1v[ct] = ln1g[ct * 16 + lr];
      b1v[ct] = ln1b[ct * 16 + lr];
      g2v[ct] = ln2g[ct * 16 + lr];
      b2v[ct] = ln2b[ct * 16 + lr];
    }
    const int bb = cb & 31;
    const int ch = cb >> 5;
    float* const obase = out + (size_t)(bb * 8 + ch) * 64 * 64;
#pragma unroll
    for (int r = 0; r < 4; ++r) {
      const int row = w * 16 + lg * 4 + r;
      float x0 = fa[0][r], x1 = fa[1][r], x2 = fa[2][r], x3 = fa[3][r];
      float mu = x0 + x1 + x2 + x3;
      mu += __shfl_xor(mu, 1); mu += __shfl_xor(mu, 2);
      mu += __shfl_xor(mu, 4); mu += __shfl_xor(mu, 8);
      mu *= 0.015625f;
      float d0 = x0 - mu, d1 = x1 - mu, d2 = x2 - mu, d3 = x3 - mu;
      float vr = d0*d0 + d1*d1 + d2*d2 + d3*d3;
      vr += __shfl_xor(vr, 1); vr += __shfl_xor(vr, 2);
      vr += __shfl_xor(vr, 4); vr += __shfl_xor(vr, 8);
      const float is1 = rsqrtf(vr * 0.015625f + 1e-6f);
      float y0 = d0*is1*g1v[0] + b1v[0];
      float y1 = d1*is1*g1v[1] + b1v[1];
      float y2 = d2*is1*g1v[2] + b1v[2];
      float y3 = d3*is1*g1v[3] + b1v[3];
      float mu2 = y0 + y1 + y2 + y3;
      mu2 += __shfl_xor(mu2, 1); mu2 += __shfl_xor(mu2, 2);
      mu2 += __shfl_xor(mu2, 4); mu2 += __shfl_xor(mu2, 8);
      mu2 *= 0.015625f;
      float e0 = y0-mu2, e1 = y1-mu2, e2 = y2-mu2, e3 = y3-mu2;
      float v2 = e0*e0 + e1*e1 + e2*e2 + e3*e3;
      v2 += __shfl_xor(v2, 1); v2 += __shfl_xor(v2, 2);
      v2 += __shfl_xor(v2, 4); v2 += __shfl_xor(v2, 8);
      const float is2 = rsqrtf(v2 * 0.015625f + 1e-6f);
      float* const op = obase + (size_t)row * 64;
      op[ 0 + lr] = e0*is2*g2v[0] + b2v[0];
      op[16 + lr] = e1*is2*g2v[1] + b2v[1];
      op[32 + lr] = e2*is2*g2v[2] + b2v[2];
      op[48 + lr] = e3*is2*g2v[3] + b2v[3];
    }
  }
}

extern "C" void kernel_launch(void* const* d_in, const int* in_sizes, int n_in,
                              void* d_out, int out_size, void* d_ws, size_t ws_size,
                              hipStream_t stream) {
  const float* gnn = (const float*)d_in[0];
  const float* Wq  = (const float*)d_in[1];
  const float* Wk  = (const float*)d_in[2];
  const float* Wv  = (const float*)d_in[3];
  const float* Wfc = (const float*)d_in[4];
  const float* l1g = (const float*)d_in[5];
  const float* l1b = (const float*)d_in[6];
  const float* l2g = (const float*)d_in[7];
  const float* l2b = (const float*)d_in[8];
  (void)in_sizes; (void)n_in; (void)out_size;

  const size_t need = ((size_t)XELEMS + WELEMS + OELEMS) * sizeof(unsigned short);
  unsigned short* wsx = (unsigned short*)d_ws;
  unsigned short* wsw = wsx + XELEMS;
  unsigned short* wso = wsw + WELEMS;

  if (d_ws != nullptr && ws_size >= need) {
    prep_x_kernel<<<dim3(1024), dim3(256), 0, stream>>>(gnn, wsx);
    prep_w_kernel<<<dim3(56), dim3(256), 0, stream>>>(Wq, Wk, Wv, Wfc, wsw);
    vlrgat_head_kernel<<<dim3(1024), dim3(512), 0, stream>>>(wsx, wsw, wso);
    fc_ln_kernel<<<dim3(256), dim3(256), 0, stream>>>(wso, wsw, l1g, l1b, l2g, l2b, (float*)d_out);
  } else {
    vlrgat_fallback<<<dim3(256), dim3(512), 0, stream>>>(
        gnn, Wq, Wk, Wv, Wfc, l1g, l1b, l2g, l2b, (float*)d_out);
  }
}

// Round 11
// 65.804 us; speedup vs baseline: 1.5015x; 1.5015x over previous
//
#include <hip/hip_runtime.h>

#define NN 256   // nodes per graph
#define DM 128   // gcn hidden dim
#define NH 4     // heads
#define LK 72    // row stride (elems) for ks/qs/P-slices
#define LT 264   // row stride for vsT/RsT

typedef __bf16 bf16;
typedef __attribute__((ext_vector_type(8))) __bf16 bf16x8;
typedef __attribute__((ext_vector_type(4))) float f32x4;
typedef __attribute__((ext_vector_type(16))) float f32x16;

static __device__ __forceinline__ unsigned short f2b(float f) {
  return __builtin_bit_cast(unsigned short, (__bf16)f);
}
static __device__ __forceinline__ bf16x8 ldf(const unsigned short* p) {
  return *(const bf16x8*)p;
}
static __device__ __forceinline__ void st4(unsigned short* p, float a, float b, float c, float d) {
  ushort4 v; v.x = f2b(a); v.y = f2b(b); v.z = f2b(c); v.w = f2b(d);
  *(ushort4*)p = v;   // single 8B LDS store
}

#define MFMA16(a,b,c) __builtin_amdgcn_mfma_f32_16x16x32_bf16((a),(b),(c),0,0,0)
#define MFMA32(a,b,c) __builtin_amdgcn_mfma_f32_32x32x16_bf16((a),(b),(c),0,0,0)
#define Z4  {0.f,0.f,0.f,0.f}
#define Z16 {0.f,0.f,0.f,0.f,0.f,0.f,0.f,0.f,0.f,0.f,0.f,0.f,0.f,0.f,0.f,0.f}

// ---- d_ws layout (unsigned short elements) ----
// x2  : [cb][dg 0..15][n 0..255][8]   size 256*16*256*8 = 8,388,608 elems
// wq2 : [dg 0..15][col 0..255][8]     at wsw+0      (32768)
// wk2 :                               at wsw+32768
// wv2 :                               at wsw+65536
// wfc2: [dg 0..31][col 0..63][8]      at wsw+98304  (16384)
#define XELEMS (256u * 16u * 256u * 8u)
#define WQO 0
#define WKO 32768
#define WVO 65536
#define WFO 98304
#define WELEMS 114688u

__global__ void prep_all_kernel(const float* __restrict__ gnn,
                                const float* __restrict__ Wq, const float* __restrict__ Wk,
                                const float* __restrict__ Wv, const float* __restrict__ Wfc,
                                unsigned short* __restrict__ x2,
                                unsigned short* __restrict__ w2) {
  if (blockIdx.x < 1024) {
    const int tid = blockIdx.x * 256 + threadIdx.x;   // 0..262143
    const int cb  = tid >> 10;
    const int r   = tid & 1023;
    const int dgq = r >> 8;        // 0..3
    const int n   = r & 255;
    const float* src = gnn + ((size_t)cb * 256 + n) * 128;
    unsigned short* dstb = x2 + (size_t)cb * (16 * 256 * 8);
#pragma unroll
    for (int i = 0; i < 4; ++i) {
      const int dg = dgq * 4 + i;
      float4 a = *(const float4*)(src + dg * 8);
      float4 b = *(const float4*)(src + dg * 8 + 4);
      ushort4 u0, u1;
      u0.x = f2b(a.x); u0.y = f2b(a.y); u0.z = f2b(a.z); u0.w = f2b(a.w);
      u1.x = f2b(b.x); u1.y = f2b(b.y); u1.z = f2b(b.z); u1.w = f2b(b.w);
      ushort4* d = (ushort4*)(dstb + ((size_t)dg * 256 + n) * 8);
      d[0] = u0; d[1] = u1;
    }
  } else {
    const int tid = (blockIdx.x - 1024) * 256 + threadIdx.x;  // 0..14335
    if (tid < 12288) {
      const int wi  = tid >> 12;          // 0:q 1:k 2:v
      const int r   = tid & 4095;
      const int dg  = r >> 8, col = r & 255;
      const float* W = (wi == 0) ? Wq : ((wi == 1) ? Wk : Wv);
      unsigned short* d = w2 + wi * 32768 + ((size_t)dg * 256 + col) * 8;
#pragma unroll
      for (int j = 0; j < 8; ++j) d[j] = f2b(W[(size_t)(dg * 8 + j) * 256 + col]);
    } else if (tid < 14336) {
      const int r  = tid - 12288;
      const int dg = r >> 6, col = r & 63;
      unsigned short* d = w2 + WFO + ((size_t)dg * 64 + col) * 8;
#pragma unroll
      for (int j = 0; j < 8; ++j) d[j] = f2b(Wfc[(size_t)(dg * 8 + j) * 64 + col]);
    }
  }
}

template<bool WS>
__global__ __launch_bounds__(512, 2)
void vlrgat_kernel(const float* __restrict__ gnn,
                   const float* __restrict__ Wq, const float* __restrict__ Wk,
                   const float* __restrict__ Wv, const float* __restrict__ Wfc,
                   const float* __restrict__ ln1g, const float* __restrict__ ln1b,
                   const float* __restrict__ ln2g, const float* __restrict__ ln2b,
                   const unsigned short* __restrict__ wsx,
                   const unsigned short* __restrict__ wsw,
                   float* __restrict__ out)
{
  __shared__ __align__(16) unsigned short ks [NN * LK];   // K  [n=256][d=64]
  __shared__ __align__(16) unsigned short qs [NN * LK];   // Q  [q=256][d=64] (pre-scaled)
  __shared__ __align__(16) unsigned short vsT[64 * LT];   // V^T [e=64][n=256]
  __shared__ __align__(16) unsigned short U  [NN * LK];   // union: P slices [256][72] | RsT [64][264] | Os [64][264]
  __shared__ __align__(16) float sums[NN];                // per-q row exp-sums

  const int t   = threadIdx.x;
  const int w   = t >> 6;     // wave 0..7
  const int l   = t & 63;
  const int lr  = l & 15;     // 16x16 helpers (epilogue)
  const int lg  = l >> 4;
  const int l31 = l & 31;     // 32x32 helpers
  const int lh  = l >> 5;
  const int g   = w & 3;      // row-group 0..3
  const int cb  = blockIdx.x;
  const unsigned short* const xw = WS ? (wsx + (size_t)cb * (16 * 256 * 8)) : nullptr;

  f32x16 oacc[NH];
#pragma unroll
  for (int h = 0; h < NH; ++h) oacc[h] = (f32x16)Z16;

  // A-fragment of x for rows n0+l31, d-cols c*16+lh*8..+7  (one b128 global load in WS mode)
  auto xfrag = [&](int n0, int c) -> bf16x8 {
    if constexpr (WS) {
      return ldf(xw + (((size_t)(c * 2 + lh)) * 256 + n0 + l31) * 8);
    } else {
      const float* p = gnn + ((size_t)cb * 256 + n0 + l31) * 128 + c * 16 + lh * 8;
      bf16x8 r;
#pragma unroll
      for (int j = 0; j < 8; ++j) r[j] = (bf16)p[j];
      return r;
    }
  };
  // weight fragment: d-rows c*16+lh*8..+7, column col
  auto wfrag = [&](int wo, const float* __restrict__ W, int c, int col) -> bf16x8 {
    if constexpr (WS) {
      return ldf(wsw + wo + (((size_t)(c * 2 + lh)) * 256 + col) * 8);
    } else {
      bf16x8 r;
#pragma unroll
      for (int j = 0; j < 8; ++j) r[j] = (bf16)W[(size_t)(c * 16 + lh * 8 + j) * 256 + col];
      return r;
    }
  };
  auto wfcfrag = [&](int kt, int col) -> bf16x8 {   // 16x16 epilogue frag (uses lg)
    if constexpr (WS) {
      return ldf(wsw + WFO + (((size_t)(kt * 4 + lg)) * 64 + col) * 8);
    } else {
      bf16x8 r;
#pragma unroll
      for (int j = 0; j < 8; ++j) r[j] = (bf16)Wfc[(size_t)(kt * 32 + lg * 8 + j) * 64 + col];
      return r;
    }
  };

#pragma unroll
  for (int h = 0; h < NH; ++h) {
    // -------- per-head fragments, issued before B1 (overlaps prev head's O-phase) ----
    const float* const WAp = (w < 4) ? Wk : Wv;
    const int       woA    = (w < 4) ? WKO : WVO;
    bf16x8 wA[2][8], wQ[8];
#pragma unroll
    for (int e = 0; e < 2; ++e)
#pragma unroll
      for (int c = 0; c < 8; ++c)
        wA[e][c] = wfrag(woA, WAp, c, h * 64 + e * 32 + l31);
    const int qcol = h * 64 + ((w < 4) ? 0 : 32) + l31;
#pragma unroll
    for (int c = 0; c < 8; ++c)
      wQ[c] = wfrag(WQO, Wq, c, qcol);

    __syncthreads();   // B1: prev head's O-phase reads of U/vsT done

    // ================= projection: K/Qe0 (waves 0-3), V/Qe1 (waves 4-7) ==========
#pragma unroll
    for (int half = 0; half < 2; ++half) {
      const int n0 = half * 128 + g * 32;
      bf16x8 xa[8];
#pragma unroll
      for (int c = 0; c < 8; ++c) xa[c] = xfrag(n0, c);
      if (w < 4) {
#pragma unroll
        for (int e = 0; e < 2; ++e) {
          f32x16 a = Z16;
#pragma unroll
          for (int c = 0; c < 8; ++c) a = MFMA32(wA[e][c], xa[c], a);
#pragma unroll
          for (int g2 = 0; g2 < 4; ++g2)
            st4(&ks[(n0 + l31) * LK + e * 32 + g2 * 8 + lh * 4],
                a[g2*4], a[g2*4+1], a[g2*4+2], a[g2*4+3]);
        }
        f32x16 a = Z16;
#pragma unroll
        for (int c = 0; c < 8; ++c) a = MFMA32(wQ[c], xa[c], a);
#pragma unroll
        for (int g2 = 0; g2 < 4; ++g2)
          st4(&qs[(n0 + l31) * LK + g2 * 8 + lh * 4],
              a[g2*4]*0.125f, a[g2*4+1]*0.125f, a[g2*4+2]*0.125f, a[g2*4+3]*0.125f);
      } else {
#pragma unroll
        for (int e = 0; e < 2; ++e) {
          f32x16 a = Z16;
#pragma unroll
          for (int c = 0; c < 8; ++c) a = MFMA32(xa[c], wA[e][c], a);
#pragma unroll
          for (int g2 = 0; g2 < 4; ++g2)
            st4(&vsT[(e * 32 + l31) * LT + n0 + g2 * 8 + lh * 4],
                a[g2*4], a[g2*4+1], a[g2*4+2], a[g2*4+3]);
        }
        f32x16 a = Z16;
#pragma unroll
        for (int c = 0; c < 8; ++c) a = MFMA32(wQ[c], xa[c], a);
#pragma unroll
        for (int g2 = 0; g2 < 4; ++g2)
          st4(&qs[(n0 + l31) * LK + 32 + g2 * 8 + lh * 4],
              a[g2*4]*0.125f, a[g2*4+1]*0.125f, a[g2*4+2]*0.125f, a[g2*4+3]*0.125f);
      }
    }
    __syncthreads();   // B3: K/Q/V published

    // ========== S^T + softmax + R, fully wave-local (no barriers) ============
    bf16x8 qf[4];
#pragma unroll
    for (int kt = 0; kt < 4; ++kt)
      qf[kt] = ldf(&qs[(w * 32 + l31) * LK + kt * 16 + lh * 8]);
    unsigned short* const Pw = &U[(w * 32) * LK];
    f32x16 racc[2]; racc[0] = (f32x16)Z16; racc[1] = (f32x16)Z16;
    float psum = 0.f;
#pragma unroll
    for (int kh = 0; kh < 2; ++kh) {
      f32x16 sh[4];
#pragma unroll
      for (int mb = 0; mb < 4; ++mb) {
        sh[mb] = (f32x16)Z16;
#pragma unroll
        for (int kt = 0; kt < 4; ++kt)
          sh[mb] = MFMA32(ldf(&ks[((kh * 4 + mb) * 32 + l31) * LK + kt * 16 + lh * 8]),
                          qf[kt], sh[mb]);
      }
#pragma unroll
      for (int mb = 0; mb < 4; ++mb)
#pragma unroll
        for (int i = 0; i < 16; ++i) {
          sh[mb][i] = __expf(sh[mb][i]);   // no max: |s| small, fp32-safe
          psum += sh[mb][i];
        }
#pragma unroll
      for (int sl = 0; sl < 2; ++sl) {
#pragma unroll
        for (int mbl = 0; mbl < 2; ++mbl) {
          const f32x16& s = sh[sl * 2 + mbl];
#pragma unroll
          for (int g2 = 0; g2 < 4; ++g2)
            st4(&Pw[l31 * LK + mbl * 32 + g2 * 8 + lh * 4],
                s[g2*4], s[g2*4+1], s[g2*4+2], s[g2*4+3]);
        }
        const int kb = kh * 128 + sl * 64;
#pragma unroll
        for (int kt2 = 0; kt2 < 4; ++kt2) {
          bf16x8 pf = ldf(&Pw[l31 * LK + kt2 * 16 + lh * 8]);
          racc[0] = MFMA32(pf, ldf(&vsT[l31 * LT + kb + kt2 * 16 + lh * 8]), racc[0]);
          racc[1] = MFMA32(pf, ldf(&vsT[(32 + l31) * LT + kb + kt2 * 16 + lh * 8]), racc[1]);
        }
      }
    }
    psum += __shfl_xor(psum, 32);
    sums[w * 32 + l31] = psum;   // both lh lanes write same value - benign

    __syncthreads();   // B4: all P-slice reads done before RsT overwrites U

    // RsT[e][q] (normalized): wave writes its q columns
#pragma unroll
    for (int g2 = 0; g2 < 4; ++g2) {
      float4 sv = *(const float4*)&sums[w * 32 + g2 * 8 + lh * 4];
      const float i0 = 1.f / sv.x, i1 = 1.f / sv.y, i2 = 1.f / sv.z, i3 = 1.f / sv.w;
#pragma unroll
      for (int eb = 0; eb < 2; ++eb)
        st4(&U[(eb * 32 + l31) * LT + w * 32 + g2 * 8 + lh * 4],
            racc[eb][g2*4]*i0, racc[eb][g2*4+1]*i1, racc[eb][g2*4+2]*i2, racc[eb][g2*4+3]*i3);
    }
    __syncthreads();   // B5: RsT published

    // ================= O = V^T @ R (waves 0-3; one 32x32 tile each) ==========
    if (w < 4) {
      const int db = (w >> 1) * 32, eb = (w & 1) * 32;
#pragma unroll
      for (int kt = 0; kt < 16; ++kt)
        oacc[h] = MFMA32(ldf(&vsT[(db + l31) * LT + kt * 16 + lh * 8]),
                         ldf(&U  [(eb + l31) * LT + kt * 16 + lh * 8]), oacc[h]);
    }
  } // h

  // ================= epilogue: Os -> @Wfc -> LN -> LN ======================
  __syncthreads();   // all O-phase U reads done
  if (w < 4) {
    const int db = (w >> 1) * 32, eb = (w & 1) * 32;
#pragma unroll
    for (int h2 = 0; h2 < NH; ++h2)
#pragma unroll
      for (int g2 = 0; g2 < 4; ++g2)
#pragma unroll
        for (int r = 0; r < 4; ++r)
          U[(db + g2 * 8 + lh * 4 + r) * LT + h2 * 64 + eb + l31] = f2b(oacc[h2][g2*4+r]);
  }
  __syncthreads();

  if (w < 4) {
    bf16x8 oa[8];
#pragma unroll
    for (int kt = 0; kt < 8; ++kt)
      oa[kt] = ldf(&U[(w * 16 + lr) * LT + kt * 32 + lg * 8]);
    f32x4 fa[4];
#pragma unroll
    for (int ct = 0; ct < 4; ++ct) {
      f32x4 a = Z4;
#pragma unroll
      for (int kt = 0; kt < 8; ++kt)
        a = MFMA16(oa[kt], wfcfrag(kt, ct * 16 + lr), a);
      fa[ct] = a;
    }

    float g1v[4], b1v[4], g2v[4], b2v[4];
#pragma unroll
    for (int ct = 0; ct < 4; ++ct) {
      g1v[ct] = ln1g[ct * 16 + lr];
      b1v[ct] = ln1b[ct * 16 + lr];
      g2v[ct] = ln2g[ct * 16 + lr];
      b2v[ct] = ln2b[ct * 16 + lr];
    }
    const int bb = cb & 31;
    const int ch = cb >> 5;
    float* const obase = out + (size_t)(bb * 8 + ch) * 64 * 64;
#pragma unroll
    for (int r = 0; r < 4; ++r) {
      const int row = w * 16 + lg * 4 + r;
      float x0 = fa[0][r], x1 = fa[1][r], x2 = fa[2][r], x3 = fa[3][r];
      float mu = x0 + x1 + x2 + x3;
      mu += __shfl_xor(mu, 1); mu += __shfl_xor(mu, 2);
      mu += __shfl_xor(mu, 4); mu += __shfl_xor(mu, 8);
      mu *= 0.015625f;
      float d0 = x0 - mu, d1 = x1 - mu, d2 = x2 - mu, d3 = x3 - mu;
      float vr = d0*d0 + d1*d1 + d2*d2 + d3*d3;
      vr += __shfl_xor(vr, 1); vr += __shfl_xor(vr, 2);
      vr += __shfl_xor(vr, 4); vr += __shfl_xor(vr, 8);
      const float is1 = rsqrtf(vr * 0.015625f + 1e-6f);
      float y0 = d0*is1*g1v[0] + b1v[0];
      float y1 = d1*is1*g1v[1] + b1v[1];
      float y2 = d2*is1*g1v[2] + b1v[2];
      float y3 = d3*is1*g1v[3] + b1v[3];
      float mu2 = y0 + y1 + y2 + y3;
      mu2 += __shfl_xor(mu2, 1); mu2 += __shfl_xor(mu2, 2);
      mu2 += __shfl_xor(mu2, 4); mu2 += __shfl_xor(mu2, 8);
      mu2 *= 0.015625f;
      float e0 = y0-mu2, e1 = y1-mu2, e2 = y2-mu2, e3 = y3-mu2;
      float v2 = e0*e0 + e1*e1 + e2*e2 + e3*e3;
      v2 += __shfl_xor(v2, 1); v2 += __shfl_xor(v2, 2);
      v2 += __shfl_xor(v2, 4); v2 += __shfl_xor(v2, 8);
      const float is2 = rsqrtf(v2 * 0.015625f + 1e-6f);
      float* const op = obase + (size_t)row * 64;
      op[ 0 + lr] = e0*is2*g2v[0] + b2v[0];
      op[16 + lr] = e1*is2*g2v[1] + b2v[1];
      op[32 + lr] = e2*is2*g2v[2] + b2v[2];
      op[48 + lr] = e3*is2*g2v[3] + b2v[3];
    }
  }
}

extern "C" void kernel_launch(void* const* d_in, const int* in_sizes, int n_in,
                              void* d_out, int out_size, void* d_ws, size_t ws_size,
                              hipStream_t stream) {
  const float* gnn = (const float*)d_in[0];
  const float* Wq  = (const float*)d_in[1];
  const float* Wk  = (const float*)d_in[2];
  const float* Wv  = (const float*)d_in[3];
  const float* Wfc = (const float*)d_in[4];
  const float* l1g = (const float*)d_in[5];
  const float* l1b = (const float*)d_in[6];
  const float* l2g = (const float*)d_in[7];
  const float* l2b = (const float*)d_in[8];
  (void)in_sizes; (void)n_in; (void)out_size;

  const size_t need = ((size_t)XELEMS + WELEMS) * sizeof(unsigned short);
  unsigned short* wsx = (unsigned short*)d_ws;
  unsigned short* wsw = wsx + XELEMS;

  if (d_ws != nullptr && ws_size >= need) {
    prep_all_kernel<<<dim3(1080), dim3(256), 0, stream>>>(gnn, Wq, Wk, Wv, Wfc, wsx, wsw);
    vlrgat_kernel<true><<<dim3(256), dim3(512), 0, stream>>>(
        gnn, Wq, Wk, Wv, Wfc, l1g, l1b, l2g, l2b, wsx, wsw, (float*)d_out);
  } else {
    vlrgat_kernel<false><<<dim3(256), dim3(512), 0, stream>>>(
        gnn, Wq, Wk, Wv, Wfc, l1g, l1b, l2g, l2b, nullptr, nullptr, (float*)d_out);
  }
}

// Round 12
// 61.635 us; speedup vs baseline: 1.6030x; 1.0676x over previous
//
#include <hip/hip_runtime.h>

#define NN 256   // nodes per graph
#define DM 128   // gcn hidden dim
#define NH 4     // heads
#define LK 72    // row stride (elems) for ks/qs/P-slices
#define LT 264   // row stride for vsT/RsT

typedef __bf16 bf16;
typedef __attribute__((ext_vector_type(8))) __bf16 bf16x8;
typedef __attribute__((ext_vector_type(4))) float f32x4;
typedef __attribute__((ext_vector_type(16))) float f32x16;

static __device__ __forceinline__ unsigned short f2b(float f) {
  return __builtin_bit_cast(unsigned short, (__bf16)f);
}
static __device__ __forceinline__ bf16x8 ldf(const unsigned short* p) {
  return *(const bf16x8*)p;
}
static __device__ __forceinline__ void st4(unsigned short* p, float a, float b, float c, float d) {
  ushort4 v; v.x = f2b(a); v.y = f2b(b); v.z = f2b(c); v.w = f2b(d);
  *(ushort4*)p = v;   // single 8B LDS store
}

#define MFMA16(a,b,c) __builtin_amdgcn_mfma_f32_16x16x32_bf16((a),(b),(c),0,0,0)
#define MFMA32(a,b,c) __builtin_amdgcn_mfma_f32_32x32x16_bf16((a),(b),(c),0,0,0)
#define Z4  {0.f,0.f,0.f,0.f}
#define Z16 {0.f,0.f,0.f,0.f,0.f,0.f,0.f,0.f,0.f,0.f,0.f,0.f,0.f,0.f,0.f,0.f}

// ---- d_ws layout (unsigned short elements) ----
// x2  : [cb][dg 0..15][n 0..255][8]   size 256*16*256*8 = 8,388,608 elems
// wq2 : [dg 0..15][col 0..255][8]     at wsw+0      (32768)
// wk2 :                               at wsw+32768
// wv2 :                               at wsw+65536
// wfc2: [dg 0..31][col 0..63][8]      at wsw+98304  (16384)
#define XELEMS (256u * 16u * 256u * 8u)
#define WQO 0
#define WKO 32768
#define WVO 65536
#define WFO 98304
#define WELEMS 114688u

__global__ void prep_all_kernel(const float* __restrict__ gnn,
                                const float* __restrict__ Wq, const float* __restrict__ Wk,
                                const float* __restrict__ Wv, const float* __restrict__ Wfc,
                                unsigned short* __restrict__ x2,
                                unsigned short* __restrict__ w2) {
  if (blockIdx.x < 1024) {
    const int tid = blockIdx.x * 256 + threadIdx.x;   // 0..262143
    const int cb  = tid >> 10;
    const int r   = tid & 1023;
    const int dgq = r >> 8;        // 0..3
    const int n   = r & 255;
    const float* src = gnn + ((size_t)cb * 256 + n) * 128;
    unsigned short* dstb = x2 + (size_t)cb * (16 * 256 * 8);
#pragma unroll
    for (int i = 0; i < 4; ++i) {
      const int dg = dgq * 4 + i;
      float4 a = *(const float4*)(src + dg * 8);
      float4 b = *(const float4*)(src + dg * 8 + 4);
      ushort4 u0, u1;
      u0.x = f2b(a.x); u0.y = f2b(a.y); u0.z = f2b(a.z); u0.w = f2b(a.w);
      u1.x = f2b(b.x); u1.y = f2b(b.y); u1.z = f2b(b.z); u1.w = f2b(b.w);
      ushort4* d = (ushort4*)(dstb + ((size_t)dg * 256 + n) * 8);
      d[0] = u0; d[1] = u1;
    }
  } else {
    const int tid = (blockIdx.x - 1024) * 256 + threadIdx.x;  // 0..14335
    if (tid < 12288) {
      const int wi  = tid >> 12;          // 0:q 1:k 2:v
      const int r   = tid & 4095;
      const int dg  = r >> 8, col = r & 255;
      const float* W = (wi == 0) ? Wq : ((wi == 1) ? Wk : Wv);
      unsigned short* d = w2 + wi * 32768 + ((size_t)dg * 256 + col) * 8;
#pragma unroll
      for (int j = 0; j < 8; ++j) d[j] = f2b(W[(size_t)(dg * 8 + j) * 256 + col]);
    } else if (tid < 14336) {
      const int r  = tid - 12288;
      const int dg = r >> 6, col = r & 63;
      unsigned short* d = w2 + WFO + ((size_t)dg * 64 + col) * 8;
#pragma unroll
      for (int j = 0; j < 8; ++j) d[j] = f2b(Wfc[(size_t)(dg * 8 + j) * 64 + col]);
    }
  }
}

template<bool WS>
__global__ __launch_bounds__(512, 1)   // LDS-bound occupancy (1 block/CU); free the register allocator
void vlrgat_kernel(const float* __restrict__ gnn,
                   const float* __restrict__ Wq, const float* __restrict__ Wk,
                   const float* __restrict__ Wv, const float* __restrict__ Wfc,
                   const float* __restrict__ ln1g, const float* __restrict__ ln1b,
                   const float* __restrict__ ln2g, const float* __restrict__ ln2b,
                   const unsigned short* __restrict__ wsx,
                   const unsigned short* __restrict__ wsw,
                   float* __restrict__ out)
{
  __shared__ __align__(16) unsigned short ks [NN * LK];   // K  [n=256][d=64]
  __shared__ __align__(16) unsigned short qs [NN * LK];   // Q  [q=256][d=64] (pre-scaled)
  __shared__ __align__(16) unsigned short vsT[64 * LT];   // V^T [e=64][n=256]
  __shared__ __align__(16) unsigned short U  [NN * LK];   // union: P slices [256][72] | RsT [64][264] | Os [64][264]
  __shared__ __align__(16) float sums[NN];                // per-q row exp-sums

  const int t   = threadIdx.x;
  const int w   = t >> 6;     // wave 0..7
  const int l   = t & 63;
  const int lr  = l & 15;     // 16x16 helpers (epilogue)
  const int lg  = l >> 4;
  const int l31 = l & 31;     // 32x32 helpers
  const int lh  = l >> 5;
  const int g   = w & 3;      // row-group 0..3
  const int cb  = blockIdx.x;
  const unsigned short* const xw = WS ? (wsx + (size_t)cb * (16 * 256 * 8)) : nullptr;

  f32x16 oacc[NH];
#pragma unroll
  for (int h = 0; h < NH; ++h) oacc[h] = (f32x16)Z16;

  // A-fragment of x for rows n0+l31, d-cols c*16+lh*8..+7  (one b128 global load in WS mode)
  auto xfrag = [&](int n0, int c) -> bf16x8 {
    if constexpr (WS) {
      return ldf(xw + (((size_t)(c * 2 + lh)) * 256 + n0 + l31) * 8);
    } else {
      const float* p = gnn + ((size_t)cb * 256 + n0 + l31) * 128 + c * 16 + lh * 8;
      bf16x8 r;
#pragma unroll
      for (int j = 0; j < 8; ++j) r[j] = (bf16)p[j];
      return r;
    }
  };
  // weight fragment: d-rows c*16+lh*8..+7, column col
  auto wfrag = [&](int wo, const float* __restrict__ W, int c, int col) -> bf16x8 {
    if constexpr (WS) {
      return ldf(wsw + wo + (((size_t)(c * 2 + lh)) * 256 + col) * 8);
    } else {
      bf16x8 r;
#pragma unroll
      for (int j = 0; j < 8; ++j) r[j] = (bf16)W[(size_t)(c * 16 + lh * 8 + j) * 256 + col];
      return r;
    }
  };
  auto wfcfrag = [&](int kt, int col) -> bf16x8 {   // 16x16 epilogue frag (uses lg)
    if constexpr (WS) {
      return ldf(wsw + WFO + (((size_t)(kt * 4 + lg)) * 64 + col) * 8);
    } else {
      bf16x8 r;
#pragma unroll
      for (int j = 0; j < 8; ++j) r[j] = (bf16)Wfc[(size_t)(kt * 32 + lg * 8 + j) * 64 + col];
      return r;
    }
  };

  // x fragments are head-invariant read-only data: load ONCE for both halves
  // (pure global reads of prep output; no LDS/barrier interaction)
  bf16x8 xaH[2][8];
#pragma unroll
  for (int half = 0; half < 2; ++half)
#pragma unroll
    for (int c = 0; c < 8; ++c)
      xaH[half][c] = xfrag(half * 128 + g * 32, c);

#pragma unroll
  for (int h = 0; h < NH; ++h) {
    // -------- per-head fragments, issued before B1 (overlaps prev head's O-phase) ----
    const float* const WAp = (w < 4) ? Wk : Wv;
    const int       woA    = (w < 4) ? WKO : WVO;
    bf16x8 wA[2][8], wQ[8];
#pragma unroll
    for (int e = 0; e < 2; ++e)
#pragma unroll
      for (int c = 0; c < 8; ++c)
        wA[e][c] = wfrag(woA, WAp, c, h * 64 + e * 32 + l31);
    const int qcol = h * 64 + ((w < 4) ? 0 : 32) + l31;
#pragma unroll
    for (int c = 0; c < 8; ++c)
      wQ[c] = wfrag(WQO, Wq, c, qcol);

    __syncthreads();   // B1: prev head's O-phase reads of U/vsT done

    // ================= projection: K/Qe0 (waves 0-3), V/Qe1 (waves 4-7) ==========
#pragma unroll
    for (int half = 0; half < 2; ++half) {
      const int n0 = half * 128 + g * 32;
      const bf16x8* xa = xaH[half];
      if (w < 4) {
#pragma unroll
        for (int e = 0; e < 2; ++e) {
          f32x16 a = Z16;
#pragma unroll
          for (int c = 0; c < 8; ++c) a = MFMA32(wA[e][c], xa[c], a);
#pragma unroll
          for (int g2 = 0; g2 < 4; ++g2)
            st4(&ks[(n0 + l31) * LK + e * 32 + g2 * 8 + lh * 4],
                a[g2*4], a[g2*4+1], a[g2*4+2], a[g2*4+3]);
        }
        f32x16 a = Z16;
#pragma unroll
        for (int c = 0; c < 8; ++c) a = MFMA32(wQ[c], xa[c], a);
#pragma unroll
        for (int g2 = 0; g2 < 4; ++g2)
          st4(&qs[(n0 + l31) * LK + g2 * 8 + lh * 4],
              a[g2*4]*0.125f, a[g2*4+1]*0.125f, a[g2*4+2]*0.125f, a[g2*4+3]*0.125f);
      } else {
#pragma unroll
        for (int e = 0; e < 2; ++e) {
          f32x16 a = Z16;
#pragma unroll
          for (int c = 0; c < 8; ++c) a = MFMA32(xa[c], wA[e][c], a);
#pragma unroll
          for (int g2 = 0; g2 < 4; ++g2)
            st4(&vsT[(e * 32 + l31) * LT + n0 + g2 * 8 + lh * 4],
                a[g2*4], a[g2*4+1], a[g2*4+2], a[g2*4+3]);
        }
        f32x16 a = Z16;
#pragma unroll
        for (int c = 0; c < 8; ++c) a = MFMA32(wQ[c], xa[c], a);
#pragma unroll
        for (int g2 = 0; g2 < 4; ++g2)
          st4(&qs[(n0 + l31) * LK + 32 + g2 * 8 + lh * 4],
              a[g2*4]*0.125f, a[g2*4+1]*0.125f, a[g2*4+2]*0.125f, a[g2*4+3]*0.125f);
      }
    }
    __syncthreads();   // B3: K/Q/V published

    // ========== S^T + softmax + R, fully wave-local (no barriers) ============
    bf16x8 qf[4];
#pragma unroll
    for (int kt = 0; kt < 4; ++kt)
      qf[kt] = ldf(&qs[(w * 32 + l31) * LK + kt * 16 + lh * 8]);
    unsigned short* const Pw = &U[(w * 32) * LK];
    f32x16 racc[2]; racc[0] = (f32x16)Z16; racc[1] = (f32x16)Z16;
    float psum = 0.f;
#pragma unroll
    for (int kh = 0; kh < 2; ++kh) {
      f32x16 sh[4];
#pragma unroll
      for (int mb = 0; mb < 4; ++mb) {
        sh[mb] = (f32x16)Z16;
#pragma unroll
        for (int kt = 0; kt < 4; ++kt)
          sh[mb] = MFMA32(ldf(&ks[((kh * 4 + mb) * 32 + l31) * LK + kt * 16 + lh * 8]),
                          qf[kt], sh[mb]);
      }
#pragma unroll
      for (int mb = 0; mb < 4; ++mb)
#pragma unroll
        for (int i = 0; i < 16; ++i) {
          sh[mb][i] = __expf(sh[mb][i]);   // no max: |s| small, fp32-safe
          psum += sh[mb][i];
        }
#pragma unroll
      for (int sl = 0; sl < 2; ++sl) {
#pragma unroll
        for (int mbl = 0; mbl < 2; ++mbl) {
          const f32x16& s = sh[sl * 2 + mbl];
#pragma unroll
          for (int g2 = 0; g2 < 4; ++g2)
            st4(&Pw[l31 * LK + mbl * 32 + g2 * 8 + lh * 4],
                s[g2*4], s[g2*4+1], s[g2*4+2], s[g2*4+3]);
        }
        const int kb = kh * 128 + sl * 64;
#pragma unroll
        for (int kt2 = 0; kt2 < 4; ++kt2) {
          bf16x8 pf = ldf(&Pw[l31 * LK + kt2 * 16 + lh * 8]);
          racc[0] = MFMA32(pf, ldf(&vsT[l31 * LT + kb + kt2 * 16 + lh * 8]), racc[0]);
          racc[1] = MFMA32(pf, ldf(&vsT[(32 + l31) * LT + kb + kt2 * 16 + lh * 8]), racc[1]);
        }
      }
    }
    psum += __shfl_xor(psum, 32);
    sums[w * 32 + l31] = psum;   // both lh lanes write same value - benign

    __syncthreads();   // B4: all P-slice reads done before RsT overwrites U

    // RsT[e][q] (normalized): wave writes its q columns
#pragma unroll
    for (int g2 = 0; g2 < 4; ++g2) {
      float4 sv = *(const float4*)&sums[w * 32 + g2 * 8 + lh * 4];
      const float i0 = 1.f / sv.x, i1 = 1.f / sv.y, i2 = 1.f / sv.z, i3 = 1.f / sv.w;
#pragma unroll
      for (int eb = 0; eb < 2; ++eb)
        st4(&U[(eb * 32 + l31) * LT + w * 32 + g2 * 8 + lh * 4],
            racc[eb][g2*4]*i0, racc[eb][g2*4+1]*i1, racc[eb][g2*4+2]*i2, racc[eb][g2*4+3]*i3);
    }
    __syncthreads();   // B5: RsT published

    // ================= O = V^T @ R (waves 0-3; one 32x32 tile each) ==========
    if (w < 4) {
      const int db = (w >> 1) * 32, eb = (w & 1) * 32;
#pragma unroll
      for (int kt = 0; kt < 16; ++kt)
        oacc[h] = MFMA32(ldf(&vsT[(db + l31) * LT + kt * 16 + lh * 8]),
                         ldf(&U  [(eb + l31) * LT + kt * 16 + lh * 8]), oacc[h]);
    }
  } // h

  // ================= epilogue: Os -> @Wfc -> LN -> LN ======================
  __syncthreads();   // all O-phase U reads done
  if (w < 4) {
    const int db = (w >> 1) * 32, eb = (w & 1) * 32;
#pragma unroll
    for (int h2 = 0; h2 < NH; ++h2)
#pragma unroll
      for (int g2 = 0; g2 < 4; ++g2)
#pragma unroll
        for (int r = 0; r < 4; ++r)
          U[(db + g2 * 8 + lh * 4 + r) * LT + h2 * 64 + eb + l31] = f2b(oacc[h2][g2*4+r]);
  }
  __syncthreads();

  if (w < 4) {
    bf16x8 oa[8];
#pragma unroll
    for (int kt = 0; kt < 8; ++kt)
      oa[kt] = ldf(&U[(w * 16 + lr) * LT + kt * 32 + lg * 8]);
    f32x4 fa[4];
#pragma unroll
    for (int ct = 0; ct < 4; ++ct) {
      f32x4 a = Z4;
#pragma unroll
      for (int kt = 0; kt < 8; ++kt)
        a = MFMA16(oa[kt], wfcfrag(kt, ct * 16 + lr), a);
      fa[ct] = a;
    }

    float g1v[4], b1v[4], g2v[4], b2v[4];
#pragma unroll
    for (int ct = 0; ct < 4; ++ct) {
      g1v[ct] = ln1g[ct * 16 + lr];
      b1v[ct] = ln1b[ct * 16 + lr];
      g2v[ct] = ln2g[ct * 16 + lr];
      b2v[ct] = ln2b[ct * 16 + lr];
    }
    const int bb = cb & 31;
    const int ch = cb >> 5;
    float* const obase = out + (size_t)(bb * 8 + ch) * 64 * 64;
#pragma unroll
    for (int r = 0; r < 4; ++r) {
      const int row = w * 16 + lg * 4 + r;
      float x0 = fa[0][r], x1 = fa[1][r], x2 = fa[2][r], x3 = fa[3][r];
      float mu = x0 + x1 + x2 + x3;
      mu += __shfl_xor(mu, 1); mu += __shfl_xor(mu, 2);
      mu += __shfl_xor(mu, 4); mu += __shfl_xor(mu, 8);
      mu *= 0.015625f;
      float d0 = x0 - mu, d1 = x1 - mu, d2 = x2 - mu, d3 = x3 - mu;
      float vr = d0*d0 + d1*d1 + d2*d2 + d3*d3;
      vr += __shfl_xor(vr, 1); vr += __shfl_xor(vr, 2);
      vr += __shfl_xor(vr, 4); vr += __shfl_xor(vr, 8);
      const float is1 = rsqrtf(vr * 0.015625f + 1e-6f);
      float y0 = d0*is1*g1v[0] + b1v[0];
      float y1 = d1*is1*g1v[1] + b1v[1];
      float y2 = d2*is1*g1v[2] + b1v[2];
      float y3 = d3*is1*g1v[3] + b1v[3];
      float mu2 = y0 + y1 + y2 + y3;
      mu2 += __shfl_xor(mu2, 1); mu2 += __shfl_xor(mu2, 2);
      mu2 += __shfl_xor(mu2, 4); mu2 += __shfl_xor(mu2, 8);
      mu2 *= 0.015625f;
      float e0 = y0-mu2, e1 = y1-mu2, e2 = y2-mu2, e3 = y3-mu2;
      float v2 = e0*e0 + e1*e1 + e2*e2 + e3*e3;
      v2 += __shfl_xor(v2, 1); v2 += __shfl_xor(v2, 2);
      v2 += __shfl_xor(v2, 4); v2 += __shfl_xor(v2, 8);
      const float is2 = rsqrtf(v2 * 0.015625f + 1e-6f);
      float* const op = obase + (size_t)row * 64;
      op[ 0 + lr] = e0*is2*g2v[0] + b2v[0];
      op[16 + lr] = e1*is2*g2v[1] + b2v[1];
      op[32 + lr] = e2*is2*g2v[2] + b2v[2];
      op[48 + lr] = e3*is2*g2v[3] + b2v[3];
    }
  }
}

extern "C" void kernel_launch(void* const* d_in, const int* in_sizes, int n_in,
                              void* d_out, int out_size, void* d_ws, size_t ws_size,
                              hipStream_t stream) {
  const float* gnn = (const float*)d_in[0];
  const float* Wq  = (const float*)d_in[1];
  const float* Wk  = (const float*)d_in[2];
  const float* Wv  = (const float*)d_in[3];
  const float* Wfc = (const float*)d_in[4];
  const float* l1g = (const float*)d_in[5];
  const float* l1b = (const float*)d_in[6];
  const float* l2g = (const float*)d_in[7];
  const float* l2b = (const float*)d_in[8];
  (void)in_sizes; (void)n_in; (void)out_size;

  const size_t need = ((size_t)XELEMS + WELEMS) * sizeof(unsigned short);
  unsigned short* wsx = (unsigned short*)d_ws;
  unsigned short* wsw = wsx + XELEMS;

  if (d_ws != nullptr && ws_size >= need) {
    prep_all_kernel<<<dim3(1080), dim3(256), 0, stream>>>(gnn, Wq, Wk, Wv, Wfc, wsx, wsw);
    vlrgat_kernel<true><<<dim3(256), dim3(512), 0, stream>>>(
        gnn, Wq, Wk, Wv, Wfc, l1g, l1b, l2g, l2b, wsx, wsw, (float*)d_out);
  } else {
    vlrgat_kernel<false><<<dim3(256), dim3(512), 0, stream>>>(
        gnn, Wq, Wk, Wv, Wfc, l1g, l1b, l2g, l2b, nullptr, nullptr, (float*)d_out);
  }
}